// Round 1
// 629.824 us; speedup vs baseline: 1.0266x; 1.0266x over previous
//
#include <hip/hip_runtime.h>
#include <cmath>

#define B_ 2
#define S_ 2048
#define D_ 1024
#define H_ 16
#define HD_ 64

typedef __attribute__((ext_vector_type(8))) short bf16x8;
typedef __attribute__((ext_vector_type(4))) short bf16x4;
typedef __attribute__((ext_vector_type(4))) float floatx4;
#define MFMA_BF16(a, b, c) __builtin_amdgcn_mfma_f32_16x16x32_bf16(a, b, c, 0, 0, 0)

// 0.125 * log2(e): folds the 1/sqrt(HD) scale AND the exp->exp2 conversion
#define QSCL 0.18033688011112042f

#if __has_builtin(__builtin_amdgcn_exp2f)
#define EXP2F(x) __builtin_amdgcn_exp2f(x)
#else
#define EXP2F(x) __expf((x) * 0.6931471805599453f)
#endif

__device__ __forceinline__ ushort f2bf(float x) {
    union { float f; unsigned u; } v; v.f = x;
    unsigned u = v.u;
    return (ushort)((u + 0x7FFFu + ((u >> 16) & 1u)) >> 16);
}
__device__ __forceinline__ float bf2f(ushort b) {
    union { unsigned u; float f; } v; v.u = ((unsigned)b) << 16;
    return v.f;
}
// packed f32x2 -> bf16x2 (RNE), lo = s0
__device__ __forceinline__ unsigned cvt_pk_bf16(float a, float b) {
    unsigned r;
    asm("v_cvt_pk_bf16_f32 %0, %1, %2" : "=v"(r) : "v"(a), "v"(b));
    return r;
}

// ---------------------------------------------------------------------------
// fp32 -> (hi, lo) bf16 split, elementwise. n4 = n/4.
// ---------------------------------------------------------------------------
__global__ __launch_bounds__(256) void f32_split_bf16(
    const float* __restrict__ in, ushort* __restrict__ hi,
    ushort* __restrict__ lo, int n4)
{
    int i = blockIdx.x * 256 + threadIdx.x;
    if (i >= n4) return;
    float4 v = ((const float4*)in)[i];
    bf16x4 h, l;
    float vv[4] = {v.x, v.y, v.z, v.w};
#pragma unroll
    for (int j = 0; j < 4; ++j) {
        ushort hb = f2bf(vv[j]);
        h[j] = (short)hb;
        l[j] = (short)f2bf(vv[j] - bf2f(hb));
    }
    ((bf16x4*)hi)[i] = h;
    ((bf16x4*)lo)[i] = l;
}

// ---------------------------------------------------------------------------
// Split-bf16 MFMA GEMM (unchanged this round).
// ---------------------------------------------------------------------------
__global__ __launch_bounds__(256, 2) void gemm_mfma_split(
    const ushort* __restrict__ Ah, const ushort* __restrict__ Al,
    const ushort* __restrict__ Wh, const ushort* __restrict__ Wl,
    const float* __restrict__ bias, float* __restrict__ C,
    int M, int N, int K)
{
    constexpr int LD = 40;  // 32 + 8 pad: stride 20 dwords -> 2-way (free)
    __shared__ ushort Ash[128][LD], Asl[128][LD], Wsh[128][LD], Wsl[128][LD];

    const int tid = threadIdx.x;
    const int lane = tid & 63;
    const int wv = tid >> 6;
    const int l15 = lane & 15;
    const int quad = lane >> 4;
    const int bm = blockIdx.y * 128;
    const int bn = blockIdx.x * 128;
    const int mw = (wv & 1) * 64;
    const int nw = (wv >> 1) * 64;

    floatx4 acc[4][4];
#pragma unroll
    for (int i = 0; i < 4; ++i)
#pragma unroll
        for (int j = 0; j < 4; ++j) acc[i][j] = (floatx4){0.f, 0.f, 0.f, 0.f};

    const int srow = tid >> 2;       // 0..63 (+64 for u=1)
    const int sc8 = (tid & 3) * 8;   // 0,8,16,24

    bf16x8 pAh[2], pAl[2], pWh[2], pWl[2];
    auto fetch = [&](int k0) {
#pragma unroll
        for (int u = 0; u < 2; ++u) {
            int r = srow + u * 64;
            pAh[u] = *(const bf16x8*)(Ah + (size_t)(bm + r) * K + k0 + sc8);
            pAl[u] = *(const bf16x8*)(Al + (size_t)(bm + r) * K + k0 + sc8);
            pWh[u] = *(const bf16x8*)(Wh + (size_t)(bn + r) * K + k0 + sc8);
            pWl[u] = *(const bf16x8*)(Wl + (size_t)(bn + r) * K + k0 + sc8);
        }
    };

    fetch(0);
    for (int k0 = 0; k0 < K; k0 += 32) {
        __syncthreads();
#pragma unroll
        for (int u = 0; u < 2; ++u) {
            int r = srow + u * 64;
            *(bf16x8*)&Ash[r][sc8] = pAh[u];
            *(bf16x8*)&Asl[r][sc8] = pAl[u];
            *(bf16x8*)&Wsh[r][sc8] = pWh[u];
            *(bf16x8*)&Wsl[r][sc8] = pWl[u];
        }
        __syncthreads();
        if (k0 + 32 < K) fetch(k0 + 32);

        bf16x8 aH[4], aL[4], bH[4], bL[4];
#pragma unroll
        for (int f = 0; f < 4; ++f) {
            aH[f] = *(const bf16x8*)&Ash[mw + f * 16 + l15][quad * 8];
            aL[f] = *(const bf16x8*)&Asl[mw + f * 16 + l15][quad * 8];
            bH[f] = *(const bf16x8*)&Wsh[nw + f * 16 + l15][quad * 8];
            bL[f] = *(const bf16x8*)&Wsl[nw + f * 16 + l15][quad * 8];
        }
#pragma unroll
        for (int mf = 0; mf < 4; ++mf)
#pragma unroll
            for (int nf = 0; nf < 4; ++nf) {
                acc[mf][nf] = MFMA_BF16(aH[mf], bH[nf], acc[mf][nf]);
                acc[mf][nf] = MFMA_BF16(aH[mf], bL[nf], acc[mf][nf]);
                acc[mf][nf] = MFMA_BF16(aL[mf], bH[nf], acc[mf][nf]);
            }
    }

#pragma unroll
    for (int mf = 0; mf < 4; ++mf)
#pragma unroll
        for (int nf = 0; nf < 4; ++nf) {
            int col = bn + nw + nf * 16 + l15;
            float bv = bias[col];
#pragma unroll
            for (int reg = 0; reg < 4; ++reg) {
                int row = bm + mw + mf * 16 + quad * 4 + reg;
                C[(size_t)row * N + col] = acc[mf][nf][reg] + bv;
            }
        }
}

// ---------------------------------------------------------------------------
// rope + head split + bf16 hi/lo split (q pre-scaled by 0.125*log2e so the
// attention can use exp2 directly), v transposed.
// ---------------------------------------------------------------------------
__global__ __launch_bounds__(256) void rope_split_bf16(
    const float* __restrict__ qkv, const float* __restrict__ sp,
    ushort* __restrict__ q_hi, ushort* __restrict__ q_lo,
    ushort* __restrict__ k_hi, ushort* __restrict__ k_lo,
    ushort* __restrict__ v_t)
{
    __shared__ ushort VT[64][72];
    const int s0 = blockIdx.x * 64;
    const int h = blockIdx.y;
    const int b = blockIdx.z;
    const int d = threadIdx.x & 63;
    const int sw = threadIdx.x >> 6;
    const float sgn = (d < 32) ? -1.f : 1.f;

#pragma unroll 4
    for (int i = 0; i < 16; ++i) {
        int sl = i * 4 + sw;
        int s = s0 + sl;
        size_t base = ((size_t)(b * S_ + s)) * (3 * D_) + h * (3 * HD_) + d;
        float tq = qkv[base];
        float tk = qkv[base + HD_];
        float tv = qkv[base + 2 * HD_];
        float spv = sp[s * HD_ + d];
        float c = cosf(spv), sn = sinf(spv);
        float pq = __shfl_xor(tq, 32);
        float pk = __shfl_xor(tk, 32);
        float qv = (tq * c + sgn * pq * sn) * QSCL;
        float kv = tk * c + sgn * pk * sn;

        size_t o = ((size_t)((b * H_ + h) * S_ + s)) * HD_ + d;
        ushort qh = f2bf(qv);
        q_hi[o] = qh; q_lo[o] = f2bf(qv - bf2f(qh));
        ushort kh = f2bf(kv);
        k_hi[o] = kh; k_lo[o] = f2bf(kv - bf2f(kh));
        VT[d][sl] = f2bf(tv);
    }
    __syncthreads();
    const int dd = threadIdx.x >> 2;
    const int c0 = (threadIdx.x & 3) * 16;
    size_t ob = ((size_t)((b * H_ + h) * HD_ + dd)) * S_ + s0 + c0;
    *(bf16x8*)(v_t + ob)     = *(const bf16x8*)&VT[dd][c0];
    *(bf16x8*)(v_t + ob + 8) = *(const bf16x8*)&VT[dd][c0 + 8];
}

// ---------------------------------------------------------------------------
// MFMA flash attention v4. Changes vs v3:
//  - BATCH-FUSED: grid (S/64, H); inner unrolled b-loop. pos_bias+mask tile
//    is fetched, masked and bf16-converted ONCE and reused for both batches
//    (halves pb HBM traffic + conversion VALU).
//  - SWAPPED QK^T: mfma(K, Q) -> S^T (col = q = l15). Each lane's 4 acc regs
//    are 4 consecutive k for one q, so Ps writes become cvt_pk + ds_write_b64
//    (was 16 scalar u16 writes + hand-RNE), and PBM is read as 4x ds_read_b64
//    (was 16 scalar reads), unpacked once, reused across both batches.
//  - exp2 domain: p = exp2(S + pbm), scale folded into q and pbm.
//  - s_setprio(1) around MFMA clusters.
// LDS: 6*9216 (K/V x2 batches) + 9728 (PBM) + 9216 (Ps) = 74240 B -> 2 blk/CU
// ---------------------------------------------------------------------------
__global__ __launch_bounds__(256, 2) void attn_flash_v4(
    const ushort* __restrict__ q_hi, const ushort* __restrict__ q_lo,
    const ushort* __restrict__ k_hi, const ushort* __restrict__ k_lo,
    const ushort* __restrict__ v_t, const float* __restrict__ pb,
    const int* __restrict__ mask,
    ushort* __restrict__ vals_hi, ushort* __restrict__ vals_lo)
{
    __shared__ ushort Kh[2][64][72];
    __shared__ ushort Kl[2][64][72];
    __shared__ ushort Vt[2][64][72];
    __shared__ ushort PBM[64][76];
    __shared__ ushort Ps[4][16][72];

    const int tid = threadIdx.x;
    const int lane = tid & 63;
    const int wv = tid >> 6;
    const int l15 = lane & 15;
    const int quad = lane >> 4;
    const int q0 = blockIdx.x * 64;
    const int h = blockIdx.y;
    const int qbase = q0 + wv * 16;

    // Q fragments, resident, both batches. Same per-lane layout serves as the
    // B operand of the swapped mfma(K, Q).
    bf16x8 qH0[2], qH1[2], qL0[2], qL1[2];
#pragma unroll
    for (int bb = 0; bb < 2; ++bb) {
        const size_t bh = ((size_t)(bb * H_ + h)) * (size_t)S_ * HD_;
        const ushort* qrh = q_hi + bh + (size_t)(qbase + l15) * HD_;
        const ushort* qrl = q_lo + bh + (size_t)(qbase + l15) * HD_;
        qH0[bb] = *(const bf16x8*)(qrh + quad * 8);
        qH1[bb] = *(const bf16x8*)(qrh + 32 + quad * 8);
        qL0[bb] = *(const bf16x8*)(qrl + quad * 8);
        qL1[bb] = *(const bf16x8*)(qrl + 32 + quad * 8);
    }

    floatx4 O4[2][4];
    float l_[2] = {0.f, 0.f};
#pragma unroll
    for (int bb = 0; bb < 2; ++bb)
#pragma unroll
        for (int f = 0; f < 4; ++f) O4[bb][f] = (floatx4){0.f, 0.f, 0.f, 0.f};

    const int kr = tid >> 3;        // 0..31 (+32)
    const int kc8 = (tid & 7) * 8;
    const int pr = tid >> 4;        // 0..15 (+16u)
    const int pc4 = (tid & 15) * 4;

    bf16x8 pKh[2][2], pKl[2][2], pVt[2][2];
    float4 pPb[4];
    int4 pMk[4];
    auto fetch = [&](int kt) {
#pragma unroll
        for (int bb = 0; bb < 2; ++bb) {
            const size_t bh = ((size_t)(bb * H_ + h)) * (size_t)S_ * HD_;
#pragma unroll
            for (int u = 0; u < 2; ++u) {
                int r = kr + u * 32;
                pKh[bb][u] = *(const bf16x8*)(k_hi + bh + (size_t)(kt + r) * HD_ + kc8);
                pKl[bb][u] = *(const bf16x8*)(k_lo + bh + (size_t)(kt + r) * HD_ + kc8);
                pVt[bb][u] = *(const bf16x8*)(v_t + bh + (size_t)r * S_ + kt + kc8);
            }
        }
#pragma unroll
        for (int u = 0; u < 4; ++u) {
            int r = pr + u * 16;
            pPb[u] = *(const float4*)(pb + ((size_t)h * S_ + q0 + r) * S_ + kt + pc4);
            pMk[u] = *(const int4*)(mask + (size_t)(q0 + r) * S_ + kt + pc4);
        }
    };

    fetch(0);
    for (int kt = 0; kt < S_; kt += 64) {
        __syncthreads();
#pragma unroll
        for (int bb = 0; bb < 2; ++bb)
#pragma unroll
            for (int u = 0; u < 2; ++u) {
                int r = kr + u * 32;
                *(bf16x8*)&Kh[bb][r][kc8] = pKh[bb][u];
                *(bf16x8*)&Kl[bb][r][kc8] = pKl[bb][u];
                *(bf16x8*)&Vt[bb][r][kc8] = pVt[bb][u];
            }
#pragma unroll
        for (int u = 0; u < 4; ++u) {
            int r = pr + u * 16;
            float w0 = pMk[u].x == 0 ? -3e30f : pPb[u].x * QSCL;
            float w1 = pMk[u].y == 0 ? -3e30f : pPb[u].y * QSCL;
            float w2 = pMk[u].z == 0 ? -3e30f : pPb[u].z * QSCL;
            float w3 = pMk[u].w == 0 ? -3e30f : pPb[u].w * QSCL;
            uint2 rr;
            rr.x = cvt_pk_bf16(w0, w1);
            rr.y = cvt_pk_bf16(w2, w3);
            *(uint2*)&PBM[r][pc4] = rr;
        }
        __syncthreads();
        if (kt + 64 < S_) fetch(kt + 64);

        // PBM unpack once, reused across both batches. Lane (l15,quad) owns
        // q = wv*16+l15, k = nf*16+quad*4+reg -> b64 per nf.
        float pbv[4][4];
#pragma unroll
        for (int nf = 0; nf < 4; ++nf) {
            bf16x4 w = *(const bf16x4*)&PBM[wv * 16 + l15][nf * 16 + quad * 4];
#pragma unroll
            for (int reg = 0; reg < 4; ++reg) pbv[nf][reg] = bf2f((ushort)w[reg]);
        }

#pragma unroll
        for (int bb = 0; bb < 2; ++bb) {
            // ---- QK^T swapped: S^T[k][q], split-bf16
            floatx4 S4[4];
            __builtin_amdgcn_s_setprio(1);
#pragma unroll
            for (int nf = 0; nf < 4; ++nf) {
                const int krow = nf * 16 + l15;
                bf16x8 bh0 = *(const bf16x8*)&Kh[bb][krow][quad * 8];
                bf16x8 bh1 = *(const bf16x8*)&Kh[bb][krow][32 + quad * 8];
                bf16x8 bl0 = *(const bf16x8*)&Kl[bb][krow][quad * 8];
                bf16x8 bl1 = *(const bf16x8*)&Kl[bb][krow][32 + quad * 8];
                floatx4 a = (floatx4){0.f, 0.f, 0.f, 0.f};
                a = MFMA_BF16(bh0, qH0[bb], a);
                a = MFMA_BF16(bh1, qH1[bb], a);
                a = MFMA_BF16(bl0, qH0[bb], a);
                a = MFMA_BF16(bl1, qH1[bb], a);
                a = MFMA_BF16(bh0, qL0[bb], a);
                a = MFMA_BF16(bh1, qL1[bb], a);
                S4[nf] = a;
            }
            __builtin_amdgcn_s_setprio(0);

            // ---- p = exp2(S^T + pbm); pack 4 consecutive k -> ds_write_b64
#pragma unroll
            for (int nf = 0; nf < 4; ++nf) {
                float p[4];
#pragma unroll
                for (int reg = 0; reg < 4; ++reg) {
                    float x = S4[nf][reg] + pbv[nf][reg];
                    p[reg] = EXP2F(x);
                    l_[bb] += p[reg];
                }
                uint2 rr;
                rr.x = cvt_pk_bf16(p[0], p[1]);
                rr.y = cvt_pk_bf16(p[2], p[3]);
                *(uint2*)&Ps[wv][l15][nf * 16 + quad * 4] = rr;
            }
            // same-wave LDS RAW: compiler inserts lgkmcnt wait, no barrier

            // ---- PV (A operand = Ps[q][k], unchanged layout)
            bf16x8 pA0 = *(const bf16x8*)&Ps[wv][l15][quad * 8];
            bf16x8 pA1 = *(const bf16x8*)&Ps[wv][l15][32 + quad * 8];
            __builtin_amdgcn_s_setprio(1);
#pragma unroll
            for (int df = 0; df < 4; ++df) {
                const int vrow = df * 16 + l15;
                bf16x8 vB0 = *(const bf16x8*)&Vt[bb][vrow][quad * 8];
                bf16x8 vB1 = *(const bf16x8*)&Vt[bb][vrow][32 + quad * 8];
                O4[bb][df] = MFMA_BF16(pA0, vB0, O4[bb][df]);
                O4[bb][df] = MFMA_BF16(pA1, vB1, O4[bb][df]);
            }
            __builtin_amdgcn_s_setprio(0);
        }
    }

    // ---- epilogue: l lives per q=l15 across quad lanes -> reduce over
    // lanes {l15, l15+16, l15+32, l15+48}, then redistribute to the C-layout
    // rows (q = quad*4+reg) via shfl from lane (quad*4+reg).
#pragma unroll
    for (int bb = 0; bb < 2; ++bb) {
        float lv = l_[bb];
        lv += __shfl_xor(lv, 16);
        lv += __shfl_xor(lv, 32);
        float linv = 1.f / lv;
#pragma unroll
        for (int reg = 0; reg < 4; ++reg) {
            float inv = __shfl(linv, quad * 4 + reg);
            const int row = qbase + quad * 4 + reg;
            size_t ob = ((size_t)(bb * S_ + row)) * D_ + h * HD_;
#pragma unroll
            for (int df = 0; df < 4; ++df) {
                float o = O4[bb][df][reg] * inv;
                ushort hb = f2bf(o);
                vals_hi[ob + df * 16 + l15] = hb;
                vals_lo[ob + df * 16 + l15] = f2bf(o - bf2f(hb));
            }
        }
    }
}

// ---------------------------------------------------------------------------
extern "C" void kernel_launch(void* const* d_in, const int* in_sizes, int n_in,
                              void* d_out, int out_size, void* d_ws, size_t ws_size,
                              hipStream_t stream) {
    const float* x      = (const float*)d_in[0];
    const float* pos_b  = (const float*)d_in[1];
    const float* sp     = (const float*)d_in[2];
    const int*   mask   = (const int*)d_in[3];
    const float* W_qkv  = (const float*)d_in[4];
    const float* b_qkv  = (const float*)d_in[5];
    const float* W_o    = (const float*)d_in[6];
    const float* b_o    = (const float*)d_in[7];
    float* out = (float*)d_out;

    char* w = (char*)d_ws;
    float*  qkv   = (float*)w;   w += (size_t)4096 * 3072 * 4;   // 48 MB
    ushort* xv_hi = (ushort*)w;  w += (size_t)4096 * 1024 * 2;   // x_hi, later vals_hi
    ushort* xv_lo = (ushort*)w;  w += (size_t)4096 * 1024 * 2;
    ushort* wq_hi = (ushort*)w;  w += (size_t)3072 * 1024 * 2;
    ushort* wq_lo = (ushort*)w;  w += (size_t)3072 * 1024 * 2;
    ushort* wo_hi = (ushort*)w;  w += (size_t)1024 * 1024 * 2;
    ushort* wo_lo = (ushort*)w;  w += (size_t)1024 * 1024 * 2;
    ushort* q_hi  = (ushort*)w;  w += (size_t)B_ * H_ * S_ * HD_ * 2;
    ushort* q_lo  = (ushort*)w;  w += (size_t)B_ * H_ * S_ * HD_ * 2;
    ushort* k_hi  = (ushort*)w;  w += (size_t)B_ * H_ * S_ * HD_ * 2;
    ushort* k_lo  = (ushort*)w;  w += (size_t)B_ * H_ * S_ * HD_ * 2;
    ushort* v_t   = (ushort*)w;  w += (size_t)B_ * H_ * S_ * HD_ * 2;

    f32_split_bf16<<<4096, 256, 0, stream>>>(x, xv_hi, xv_lo, 4096 * 1024 / 4);
    f32_split_bf16<<<3072, 256, 0, stream>>>(W_qkv, wq_hi, wq_lo, 3072 * 1024 / 4);
    f32_split_bf16<<<1024, 256, 0, stream>>>(W_o, wo_hi, wo_lo, 1024 * 1024 / 4);

    gemm_mfma_split<<<dim3(3072 / 128, 4096 / 128), 256, 0, stream>>>(
        xv_hi, xv_lo, wq_hi, wq_lo, b_qkv, qkv, 4096, 3072, 1024);

    rope_split_bf16<<<dim3(S_ / 64, H_, B_), 256, 0, stream>>>(
        qkv, sp, q_hi, q_lo, k_hi, k_lo, v_t);

    // vals (hi/lo) overwrite the x split buffers (x fully consumed by gemm1)
    attn_flash_v4<<<dim3(S_ / 64, H_), 256, 0, stream>>>(
        q_hi, q_lo, k_hi, k_lo, v_t, pos_b, mask, xv_hi, xv_lo);

    gemm_mfma_split<<<dim3(1024 / 128, 4096 / 128), 256, 0, stream>>>(
        xv_hi, xv_lo, wo_hi, wo_lo, b_o, out, 4096, 1024, 1024);
}